// Round 4
// baseline (359.317 us; speedup 1.0000x reference)
//
#include <hip/hip_runtime.h>
#include <math.h>

// Problem constants (fixed-shape problem)
#define B_  16
#define D_  37
#define F_  4096
#define I_  64
#define EPS 1e-5f
// softmax scale 1/sqrt(64) folded with log2(e) into q at projection time,
// so S_mfma = att*log2e and softmax is a raw exp2.
#define QSCALE 0.18033688011112042f
#define NQS 2           // stats q-split (partial-Z planes)

typedef unsigned short u16;
typedef __bf16 bf16x8 __attribute__((ext_vector_type(8)));
typedef float  f32x16 __attribute__((ext_vector_type(16)));

#define ZERO16 {0,0,0,0, 0,0,0,0, 0,0,0,0, 0,0,0,0}
#define MFMA32(a, b, c) __builtin_amdgcn_mfma_f32_32x32x16_bf16((a), (b), (c), 0, 0, 0)

// raw hardware transcendentals (1 instr) with safe fallbacks
#if __has_builtin(__builtin_amdgcn_exp2f)
#define EX2(x) __builtin_amdgcn_exp2f(x)
#else
#define EX2(x) exp2f(x)
#endif
#if __has_builtin(__builtin_amdgcn_logf)
#define LG2(x) __builtin_amdgcn_logf(x)
#else
#define LG2(x) log2f(x)
#endif

// fp32 -> bf16 RNE (for q/k/v)
__device__ __forceinline__ u16 f2b(float f) {
  unsigned u = __builtin_bit_cast(unsigned, f);
  return (u16)((u + 0x7fffu + ((u >> 16) & 1u)) >> 16);
}
// fp32 -> bf16 round-half-up (2 ops, bias-free to 0.5ulp; P >= 0 always)
__device__ __forceinline__ u16 f2b_ru(float f) {
  unsigned u = __builtin_bit_cast(unsigned, f);
  return (u16)((u + 0x8000u) >> 16);
}

// ---------------------------------------------------------------------------
// Swizzled LDS tiles: logical [rows][64] bf16, elem (r,c) at
//   r*64 + ((c>>3 ^ (r&7))<<3) + (c&7)
// -> 16B-aligned b128 reads AND conflict-free banks without padding.
// ---------------------------------------------------------------------------
__device__ __forceinline__ bf16x8 ldfrag(const u16* base, int row, int kb) {
  return *(const bf16x8*)(base + (row << 6) + ((kb ^ (row & 7)) << 3));
}
__device__ __forceinline__ void stage16(u16* dst, const u16* src, int c, int spitch) {
  const int r = c >> 3, cb = c & 7;
  const int4 v = *(const int4*)(src + (size_t)r * spitch + (cb << 3));
  *(int4*)(dst + (r << 6) + ((cb ^ (r & 7)) << 3)) = v;
}

// ---------------------------------------------------------------------------
// Kernel 1: qkv projection + LayerNorm -> bf16. q pre-scaled by QSCALE.
// v written transposed vt[b][i][f] for kernel 3's B-fragments.
// ---------------------------------------------------------------------------
__global__ __launch_bounds__(256) void qkv_ln_k(
    const float* __restrict__ x,
    const float* __restrict__ Wq, const float* __restrict__ Wk,
    const float* __restrict__ Wv,
    u16* __restrict__ qn, u16* __restrict__ kn, u16* __restrict__ vt) {
  __shared__ float sW[3 * D_ * I_];
  __shared__ float xs[D_ * 64];
  __shared__ __align__(16) u16 vtile[64 * 72];

  const int t = threadIdx.x;
  const int b = blockIdx.y;
  const int f0 = blockIdx.x * 64;

  for (int i = t; i < D_ * I_; i += 256) {
    sW[i]               = Wq[i];
    sW[D_ * I_ + i]     = Wk[i];
    sW[2 * D_ * I_ + i] = Wv[i];
  }
  const float* xb = x + (size_t)b * D_ * F_ + f0;
  for (int i = t; i < D_ * 64; i += 256)
    xs[i] = xb[(size_t)(i >> 6) * F_ + (i & 63)];
  __syncthreads();

  const int lane = t & 63, w = t >> 6;

  for (int it = 0; it < 16; ++it) {
    const int fl = w * 16 + it;
    float hq = 0.f, hk = 0.f, hv = 0.f;
#pragma unroll
    for (int d = 0; d < D_; ++d) {
      const float xv = xs[d * 64 + fl];
      hq = fmaf(xv, sW[d * 64 + lane], hq);
      hk = fmaf(xv, sW[D_ * I_ + d * 64 + lane], hk);
      hv = fmaf(xv, sW[2 * D_ * I_ + d * 64 + lane], hv);
    }
    auto lnorm = [&](float a) -> float {
      float s = a;
#pragma unroll
      for (int o = 32; o > 0; o >>= 1) s += __shfl_xor(s, o, 64);
      const float mu = s * (1.f / 64.f);
      const float d0 = a - mu;
      float v = d0 * d0;
#pragma unroll
      for (int o = 32; o > 0; o >>= 1) v += __shfl_xor(v, o, 64);
      return d0 * rsqrtf(v * (1.f / 64.f) + EPS);
    };
    const size_t fo = ((size_t)b * F_ + f0 + fl) * I_ + lane;
    qn[fo] = f2b(lnorm(hq) * QSCALE);
    kn[fo] = f2b(lnorm(hk));
    vtile[lane * 72 + fl] = f2b(lnorm(hv));
  }
  __syncthreads();
  for (int p = 0; p < 2; ++p) {
    const int c = p * 256 + t;
    const int r = c >> 3, off = (c & 7) * 8;
    const int4 v = *(const int4*)&vtile[r * 72 + off];
    *(int4*)(vt + ((size_t)b * I_ + r) * F_ + f0 + off) = v;
  }
}

// ---------------------------------------------------------------------------
// Kernel 2: partial column-softmax sums. zp[qh][b][k] = sum_{q in half}
// exp2(S). Block: 512 thr (8 waves), (b, 256-k tile, q-half). K-tile staged
// once -> K-fragments hoisted to registers -> LDS reused as double-buffered
// Q stream, one barrier per 64-q chunk. (No LDS-pointer arrays: gfx950
// rejects addrspacecast static initializers -- compute offsets per iter.)
// ---------------------------------------------------------------------------
__global__ __launch_bounds__(512, 4) void attn_stats_k(
    const u16* __restrict__ qn, const u16* __restrict__ kn,
    float* __restrict__ zp) {
  __shared__ __align__(16) u16 sm[16384];   // 32 KB

  const int t = threadIdx.x, lane = t & 63, w = t >> 6;
  const int l31 = lane & 31, lh = lane >> 5;
  const int b = blockIdx.y, k0 = blockIdx.x * 256, qh = blockIdx.z;

  // stage K 256x64 (2048 16B-chunks, 4/thread), hoist own fragments
  const u16* kb = kn + ((size_t)b * F_ + k0) * I_;
#pragma unroll
  for (int p = 0; p < 4; ++p) stage16(sm, kb, p * 512 + t, 64);
  __syncthreads();
  const u16* myK = sm + (w * 32) * 64;      // w*32 % 8 == 0: swizzle-consistent
  bf16x8 kf[4];
#pragma unroll
  for (int ic = 0; ic < 4; ++ic) kf[ic] = ldfrag(myK, l31, ic * 2 + lh);
  __syncthreads();                          // all frag reads done before reuse

  const u16* qb = qn + ((size_t)b * F_ + qh * (F_ / NQS)) * I_;
  stage16(sm, qb, t, 64);                   // chunk 0 into buffer 0

  float Zc[4] = {0.f, 0.f, 0.f, 0.f};
  const int NC = F_ / NQS / 64;             // 32 chunks

  for (int c = 0; c < NC; ++c) {
    const u16* cur = sm + (c & 1) * 4096;
    u16* nxt = sm + ((c & 1) ^ 1) * 4096;
    __syncthreads();                        // cur staged; nxt's old readers done
    if (c + 1 < NC) stage16(nxt, qb + (size_t)(c + 1) * 64 * I_, t, 64);

    f32x16 a0 = ZERO16, a1 = ZERO16;
#pragma unroll
    for (int ic = 0; ic < 4; ++ic) {
      const bf16x8 q0f = ldfrag(cur, l31, ic * 2 + lh);
      const bf16x8 q1f = ldfrag(cur + 32 * 64, l31, ic * 2 + lh);
      a0 = MFMA32(q0f, kf[ic], a0);
      a1 = MFMA32(q1f, kf[ic], a1);
    }
#pragma unroll
    for (int r = 0; r < 16; ++r) {
      Zc[r & 3] += EX2(a0[r]);
      Zc[r & 3] += EX2(a1[r]);
    }
  }

  float Zt = (Zc[0] + Zc[1]) + (Zc[2] + Zc[3]);
  Zt += __shfl_xor(Zt, 32, 64);
  if (lane < 32)
    zp[((size_t)qh * B_ + b) * F_ + k0 + w * 32 + lane] = Zt;
}

// ---------------------------------------------------------------------------
// Kernel 3: out[q,i] = sum_k exp2(S - log2 Z_k) * v[k,i].
// Block: 512 thr (8 waves), (b, 256-q tile). Q-fragments hoisted to regs
// (LDS staging area reused as double-buffered K/VT chunks, 1 barrier/chunk).
// Per 64-k chunk: S-MFMA, p=exp2(s-L) -> bf16 -> per-wave LDS P, PV-MFMA.
// LDS layout (u16 elems): K dbuf @ 0/4096, VT dbuf @ 8192/12288, P @ 16384.
// ---------------------------------------------------------------------------
__global__ __launch_bounds__(512, 4) void attn_out_k(
    const u16* __restrict__ qn, const u16* __restrict__ kn,
    const u16* __restrict__ vt, const float* __restrict__ zp,
    float* __restrict__ out) {
  __shared__ __align__(16) u16 sm[32768];   // 64 KB

  const int t = threadIdx.x, lane = t & 63, w = t >> 6;
  const int l31 = lane & 31, lh = lane >> 5;
  const int b = blockIdx.y, q0 = blockIdx.x * 256;

  // stage Q 256x64 into sm[0..16384), hoist own A-fragments
  const u16* qb = qn + ((size_t)b * F_ + q0) * I_;
#pragma unroll
  for (int p = 0; p < 4; ++p) stage16(sm, qb, p * 512 + t, 64);
  __syncthreads();
  const u16* myQ = sm + (w * 32) * 64;
  bf16x8 qf[4];
#pragma unroll
  for (int ic = 0; ic < 4; ++ic) qf[ic] = ldfrag(myQ, l31, ic * 2 + lh);
  __syncthreads();                          // frag reads done before overwrite

  const u16* kbase = kn + (size_t)b * F_ * I_;
  const u16* vbase = vt + (size_t)b * I_ * F_;
  const float* zpb = zp + (size_t)b * F_;
  u16* Pw = sm + 16384 + w * 2048;

  // stage chunk 0 into buffers 0
  stage16(sm, kbase, t, 64);
  stage16(sm + 8192, vbase, t, F_);

  f32x16 o0 = ZERO16, o1 = ZERO16;

  for (int c = 0; c < F_ / 64; ++c) {
    const int cur = (c & 1) * 4096;
    const int nxt = cur ^ 4096;
    __syncthreads();                        // buf[cur] staged; old readers done
    if (c + 1 < F_ / 64) {
      stage16(sm + nxt, kbase + (size_t)(c + 1) * 64 * I_, t, 64);
      stage16(sm + 8192 + nxt, vbase + (size_t)(c + 1) * 64, t, F_);
    }

    // column log-sums: L = log2(sum of partial Z planes)
    const int kg = c * 64 + l31;
    const float La = LG2(zpb[kg] + zpb[(size_t)B_ * F_ + kg]);
    const float Lb = LG2(zpb[kg + 32] + zpb[(size_t)B_ * F_ + kg + 32]);

    // S = Q(own 32q) x K^T : two 32x32 blocks (k-halves)
    const u16* Kc = sm + cur;
    f32x16 s0 = ZERO16, s1 = ZERO16;
#pragma unroll
    for (int ic = 0; ic < 4; ++ic) {
      const bf16x8 bk0 = ldfrag(Kc, l31, ic * 2 + lh);
      const bf16x8 bk1 = ldfrag(Kc + 32 * 64, l31, ic * 2 + lh);
      s0 = MFMA32(qf[ic], bk0, s0);
      s1 = MFMA32(qf[ic], bk1, s1);
    }

    // P = exp2(s - L) -> bf16 into own wave's P region (swizzled [q][k])
#pragma unroll
    for (int r = 0; r < 16; ++r) {
      const int qr = (r & 3) + 8 * (r >> 2) + 4 * lh;   // C/D row mapping
      const int ka = l31, kb2 = 32 + l31;
      Pw[(qr << 6) + (((ka >> 3) ^ (qr & 7)) << 3) + (ka & 7)]   = f2b_ru(EX2(s0[r] - La));
      Pw[(qr << 6) + (((kb2 >> 3) ^ (qr & 7)) << 3) + (kb2 & 7)] = f2b_ru(EX2(s1[r] - Lb));
    }
    // same-wave LDS write->read: in-order DS pipe + compiler lgkmcnt

    // O += P(32q x 64k) * V(64k x 64i), two i-halves
    const u16* Vc = sm + 8192 + cur;
#pragma unroll
    for (int kc = 0; kc < 4; ++kc) {
      const bf16x8 ap  = ldfrag(Pw, l31, kc * 2 + lh);
      const bf16x8 bv0 = ldfrag(Vc, l31, kc * 2 + lh);
      const bf16x8 bv1 = ldfrag(Vc + 32 * 64, l31, kc * 2 + lh);
      o0 = MFMA32(ap, bv0, o0);
      o1 = MFMA32(ap, bv1, o1);
    }
  }

  float* ob = out + ((size_t)b * F_ + q0 + w * 32) * I_;
#pragma unroll
  for (int r = 0; r < 16; ++r) {
    const int qr = (r & 3) + 8 * (r >> 2) + 4 * lh;
    ob[(size_t)qr * I_ + l31]      = o0[r];
    ob[(size_t)qr * I_ + 32 + l31] = o1[r];
  }
}

// ---------------------------------------------------------------------------
extern "C" void kernel_launch(void* const* d_in, const int* in_sizes, int n_in,
                              void* d_out, int out_size, void* d_ws,
                              size_t ws_size, hipStream_t stream) {
  const float* x  = (const float*)d_in[0];
  const float* Wq = (const float*)d_in[1];
  const float* Wk = (const float*)d_in[2];
  const float* Wv = (const float*)d_in[3];
  float* out = (float*)d_out;

  // workspace: qn, kn (bf16 [b][f][64]); vt (bf16 [b][i][4096]);
  //            zp (f32 [NQS][b][f] partial column sums)
  u16* qn   = (u16*)d_ws;
  u16* kn   = qn + (size_t)B_ * F_ * I_;
  u16* vt   = kn + (size_t)B_ * F_ * I_;
  float* zp = (float*)(vt + (size_t)B_ * F_ * I_);

  qkv_ln_k<<<dim3(F_ / 64, B_), 256, 0, stream>>>(x, Wq, Wk, Wv, qn, kn, vt);
  attn_stats_k<<<dim3(F_ / 256, B_, NQS), 512, 0, stream>>>(qn, kn, zp);
  attn_out_k<<<dim3(F_ / 256, B_), 512, 0, stream>>>(qn, kn, vt, zp, out);
}

// Round 5
// 258.005 us; speedup vs baseline: 1.3927x; 1.3927x over previous
//
#include <hip/hip_runtime.h>
#include <math.h>

// Problem constants (fixed-shape problem)
#define B_  16
#define D_  37
#define F_  4096
#define I_  64
#define EPS 1e-5f
// softmax scale 1/sqrt(64) folded with log2(e) into q at projection time,
// so S_mfma = att*log2e and softmax is a raw exp2. |att|<=8 (LN rows have
// norm exactly 8) -> exp2(S) <= 2^11.6: no max pass, bf16-safe unnormalized P.
#define QSCALE 0.18033688011112042f
#define NQS 2           // stats q-split (partial-Z planes)

typedef unsigned short u16;
typedef __bf16 bf16x8 __attribute__((ext_vector_type(8)));
typedef float  f32x16 __attribute__((ext_vector_type(16)));
typedef unsigned int u32x4 __attribute__((ext_vector_type(4)));
typedef int i32x2 __attribute__((ext_vector_type(2)));

#define ZERO16 {0,0,0,0, 0,0,0,0, 0,0,0,0, 0,0,0,0}
#define MFMA32(a, b, c) __builtin_amdgcn_mfma_f32_32x32x16_bf16((a), (b), (c), 0, 0, 0)

#if __has_builtin(__builtin_amdgcn_exp2f)
#define EX2(x) __builtin_amdgcn_exp2f(x)
#else
#define EX2(x) exp2f(x)
#endif
#if __has_builtin(__builtin_amdgcn_rcpf)
#define RCP(x) __builtin_amdgcn_rcpf(x)
#else
#define RCP(x) (1.f / (x))
#endif

// fp32 -> bf16 RNE
__device__ __forceinline__ u16 f2b(float f) {
  unsigned u = __builtin_bit_cast(unsigned, f);
  return (u16)((u + 0x7fffu + ((u >> 16) & 1u)) >> 16);
}
// pack two fp32 -> bf16x2 in one u32 (round-half-up; inputs are exp2 outputs > 0)
__device__ __forceinline__ unsigned pk2(float lo, float hi) {
  unsigned a = __builtin_bit_cast(unsigned, lo);
  unsigned b = __builtin_bit_cast(unsigned, hi);
  return ((b + 0x8000u) & 0xffff0000u) | ((a + 0x8000u) >> 16);
}

// half-wave register swap: a' = [a(lanes0-31) | b(lanes0-31)],
//                          b' = [a(lanes32-63) | b(lanes32-63)]
// (v_permlane32_swap_b32 on gfx950; ds_permute-based shfl fallback)
__device__ __forceinline__ void plswap(unsigned& a, unsigned& b) {
#if __has_builtin(__builtin_amdgcn_permlane32_swap)
  i32x2 r = __builtin_amdgcn_permlane32_swap((int)a, (int)b, false, false);
  a = (unsigned)r[0];
  b = (unsigned)r[1];
#else
  const int lh = (int)((threadIdx.x & 63) >> 5);
  unsigned pa = (unsigned)__shfl_xor((int)a, 32, 64);
  unsigned pb = (unsigned)__shfl_xor((int)b, 32, 64);
  unsigned na = lh ? pb : a;
  unsigned nb = lh ? b : pa;
  a = na;
  b = nb;
#endif
}

// From one S^T 32x32 C-block (rows=k, cols=q: lane holds q=lane&31, 16 k's),
// build two PV A-fragments (m=q, contraction k): f0 covers k_blk 0..15,
// f1 covers 16..31 (relative to this C-block's 32 k-rows).
// C-reg r holds k = (r&3) + 8*(r>>2) + 4*lh; A-frag VGPR j needs k = lh*8+2j(+1).
__device__ __forceinline__ void build_af(const f32x16& s, bf16x8& f0, bf16x8& f1) {
  float e[16];
#pragma unroll
  for (int r = 0; r < 16; ++r) e[r] = EX2(s[r]);
  unsigned a = pk2(e[0], e[1]),   bq = pk2(e[2], e[3]);
  unsigned c = pk2(e[4], e[5]),   d  = pk2(e[6], e[7]);
  plswap(a, c);
  plswap(bq, d);
  u32x4 v0 = {a, bq, c, d};
  f0 = __builtin_bit_cast(bf16x8, v0);
  unsigned ee = pk2(e[8], e[9]),  ff = pk2(e[10], e[11]);
  unsigned g  = pk2(e[12], e[13]), h = pk2(e[14], e[15]);
  plswap(ee, g);
  plswap(ff, h);
  u32x4 v1 = {ee, ff, g, h};
  f1 = __builtin_bit_cast(bf16x8, v1);
}

// ---------------------------------------------------------------------------
// Swizzled LDS tiles: logical [rows][64] bf16, elem (r,c) at
//   r*64 + ((c>>3 ^ (r&7))<<3) + (c&7)
// -> 16B-aligned b128 reads AND conflict-free banks without padding.
// ---------------------------------------------------------------------------
__device__ __forceinline__ bf16x8 ldfrag(const u16* base, int row, int kb) {
  return *(const bf16x8*)(base + (row << 6) + ((kb ^ (row & 7)) << 3));
}
__device__ __forceinline__ void stage16(u16* dst, const u16* src, int c, int spitch) {
  const int r = c >> 3, cb = c & 7;
  const int4 v = *(const int4*)(src + (size_t)r * spitch + (cb << 3));
  *(int4*)(dst + (r << 6) + ((cb ^ (r & 7)) << 3)) = v;
}

// ---------------------------------------------------------------------------
// Kernel 1: qkv projection + LayerNorm -> bf16. q pre-scaled by QSCALE.
// v written transposed vt[b][i][f] for kernel 4's B-fragments.
// ---------------------------------------------------------------------------
__global__ __launch_bounds__(256) void qkv_ln_k(
    const float* __restrict__ x,
    const float* __restrict__ Wq, const float* __restrict__ Wk,
    const float* __restrict__ Wv,
    u16* __restrict__ qn, u16* __restrict__ kn, u16* __restrict__ vt) {
  __shared__ float sW[3 * D_ * I_];
  __shared__ float xs[D_ * 64];
  __shared__ __align__(16) u16 vtile[64 * 72];

  const int t = threadIdx.x;
  const int b = blockIdx.y;
  const int f0 = blockIdx.x * 64;

  for (int i = t; i < D_ * I_; i += 256) {
    sW[i]               = Wq[i];
    sW[D_ * I_ + i]     = Wk[i];
    sW[2 * D_ * I_ + i] = Wv[i];
  }
  const float* xb = x + (size_t)b * D_ * F_ + f0;
  for (int i = t; i < D_ * 64; i += 256)
    xs[i] = xb[(size_t)(i >> 6) * F_ + (i & 63)];
  __syncthreads();

  const int lane = t & 63, w = t >> 6;

  for (int it = 0; it < 16; ++it) {
    const int fl = w * 16 + it;
    float hq = 0.f, hk = 0.f, hv = 0.f;
#pragma unroll
    for (int d = 0; d < D_; ++d) {
      const float xv = xs[d * 64 + fl];
      hq = fmaf(xv, sW[d * 64 + lane], hq);
      hk = fmaf(xv, sW[D_ * I_ + d * 64 + lane], hk);
      hv = fmaf(xv, sW[2 * D_ * I_ + d * 64 + lane], hv);
    }
    auto lnorm = [&](float a) -> float {
      float s = a;
#pragma unroll
      for (int o = 32; o > 0; o >>= 1) s += __shfl_xor(s, o, 64);
      const float mu = s * (1.f / 64.f);
      const float d0 = a - mu;
      float v = d0 * d0;
#pragma unroll
      for (int o = 32; o > 0; o >>= 1) v += __shfl_xor(v, o, 64);
      return d0 * rsqrtf(v * (1.f / 64.f) + EPS);
    };
    const size_t fo = ((size_t)b * F_ + f0 + fl) * I_ + lane;
    qn[fo] = f2b(lnorm(hq) * QSCALE);
    kn[fo] = f2b(lnorm(hk));
    vtile[lane * 72 + fl] = f2b(lnorm(hv));
  }
  __syncthreads();
  for (int p = 0; p < 2; ++p) {
    const int c = p * 256 + t;
    const int r = c >> 3, off = (c & 7) * 8;
    const int4 v = *(const int4*)&vtile[r * 72 + off];
    *(int4*)(vt + ((size_t)b * I_ + r) * F_ + f0 + off) = v;
  }
}

// ---------------------------------------------------------------------------
// Kernel 2: partial column-softmax sums. zp[qh][b][k] = sum_{q in half}
// exp2(S). 512 thr (8 waves), (b, 256-k tile, q-half). K-frags hoisted,
// Q double-buffered, one barrier per 64-q chunk.
// ---------------------------------------------------------------------------
__global__ __launch_bounds__(512, 4) void attn_stats_k(
    const u16* __restrict__ qn, const u16* __restrict__ kn,
    float* __restrict__ zp) {
  __shared__ __align__(16) u16 sm[16384];   // 32 KB

  const int t = threadIdx.x, lane = t & 63, w = t >> 6;
  const int l31 = lane & 31, lh = lane >> 5;
  const int b = blockIdx.y, k0 = blockIdx.x * 256, qh = blockIdx.z;

  const u16* kb = kn + ((size_t)b * F_ + k0) * I_;
#pragma unroll
  for (int p = 0; p < 4; ++p) stage16(sm, kb, p * 512 + t, 64);
  __syncthreads();
  const u16* myK = sm + (w * 32) * 64;      // w*32 % 8 == 0: swizzle-consistent
  bf16x8 kf[4];
#pragma unroll
  for (int ic = 0; ic < 4; ++ic) kf[ic] = ldfrag(myK, l31, ic * 2 + lh);
  __syncthreads();                          // all frag reads done before reuse

  const u16* qb = qn + ((size_t)b * F_ + qh * (F_ / NQS)) * I_;
  stage16(sm, qb, t, 64);                   // chunk 0 into buffer 0

  float Zc[4] = {0.f, 0.f, 0.f, 0.f};
  const int NC = F_ / NQS / 64;             // 32 chunks

  for (int c = 0; c < NC; ++c) {
    const u16* cur = sm + (c & 1) * 4096;
    u16* nxt = sm + ((c & 1) ^ 1) * 4096;
    __syncthreads();                        // cur staged; nxt's old readers done
    if (c + 1 < NC) stage16(nxt, qb + (size_t)(c + 1) * 64 * I_, t, 64);

    f32x16 a0 = ZERO16, a1 = ZERO16;
#pragma unroll
    for (int ic = 0; ic < 4; ++ic) {
      const bf16x8 q0f = ldfrag(cur, l31, ic * 2 + lh);
      const bf16x8 q1f = ldfrag(cur + 32 * 64, l31, ic * 2 + lh);
      a0 = MFMA32(q0f, kf[ic], a0);
      a1 = MFMA32(q1f, kf[ic], a1);
    }
#pragma unroll
    for (int r = 0; r < 16; ++r) {
      Zc[r & 3] += EX2(a0[r]);
      Zc[r & 3] += EX2(a1[r]);
    }
  }

  float Zt = (Zc[0] + Zc[1]) + (Zc[2] + Zc[3]);
  Zt += __shfl_xor(Zt, 32, 64);
  if (lane < 32)
    zp[((size_t)qh * B_ + b) * F_ + k0 + w * 32 + lane] = Zt;
}

// ---------------------------------------------------------------------------
// Kernel 3: fold 1/Z_k into V rows, in place: vt[b][i][k] *= 1/(zp0+zp1)[b][k].
// ---------------------------------------------------------------------------
__global__ __launch_bounds__(256) void vscale_k(u16* __restrict__ vt,
                                                const float* __restrict__ zp) {
  const int b = blockIdx.y;
  const int off = (blockIdx.x * 256 + (int)threadIdx.x) * 8;  // within I_*F_
  const int k = off & (F_ - 1);
  u16* p = vt + (size_t)b * I_ * F_ + off;
  const float* z0 = zp + (size_t)b * F_ + k;
  const float* z1 = zp + (size_t)B_ * F_ + (size_t)b * F_ + k;
  int4 raw = *(const int4*)p;
  u16 es[8], os[8];
  *(int4*)es = raw;
#pragma unroll
  for (int j = 0; j < 8; ++j) {
    const float v = __builtin_bit_cast(float, (unsigned)es[j] << 16);
    const float rz = RCP(z0[j] + z1[j]);
    os[j] = f2b(v * rz);
  }
  *(int4*)p = *(int4*)os;
}

// ---------------------------------------------------------------------------
// Kernel 4: partial out over a k-half: out[q,i] = sum_k exp2(S_qk) * v'[k,i].
// 256 thr (4 waves), (128-q tile, b, k-split). S computed TRANSPOSED
// (A=K rows=k, B=own-Q cols=q) so exp2'd C-regs repack in-register (permlane
// swaps) into PV A-fragments -- no P LDS round-trip. Q-frags hoisted; K/VT
// double-buffered in 32 KB LDS; one barrier per 64-k chunk.
// ks=0 writes d_out, ks=1 writes partial; reduce_k sums.
// ---------------------------------------------------------------------------
__global__ __launch_bounds__(256, 3) void attn_out_k(
    const u16* __restrict__ qn, const u16* __restrict__ kn,
    const u16* __restrict__ vt, float* __restrict__ outp,
    float* __restrict__ pout) {
  __shared__ __align__(16) u16 sm[16384];  // 32 KB: Q-stage/K dbuf @0/4096, VT dbuf @8192/12288

  const int t = threadIdx.x, lane = t & 63, w = t >> 6;
  const int l31 = lane & 31, lh = lane >> 5;
  const int b = blockIdx.y, q0 = blockIdx.x * 128, ks = blockIdx.z;

  // stage Q 128x64, hoist own 32-q B-fragments, then reuse region for K dbuf
  const u16* qb = qn + ((size_t)b * F_ + q0) * I_;
#pragma unroll
  for (int p = 0; p < 4; ++p) stage16(sm, qb, p * 256 + t, 64);
  __syncthreads();
  const u16* myQ = sm + (w * 32) * 64;     // w*32 % 8 == 0: swizzle-consistent
  bf16x8 qf[4];
#pragma unroll
  for (int ic = 0; ic < 4; ++ic) qf[ic] = ldfrag(myQ, l31, ic * 2 + lh);
  __syncthreads();                         // frag reads done before overwrite

  const u16* kbase = kn + ((size_t)b * F_ + ks * (F_ / 2)) * I_;
  const u16* vbase = vt + (size_t)b * I_ * F_ + ks * (F_ / 2);

  // stage chunk 0 into buffers 0
#pragma unroll
  for (int p = 0; p < 2; ++p) {
    stage16(sm, kbase, p * 256 + t, 64);
    stage16(sm + 8192, vbase, p * 256 + t, F_);
  }

  f32x16 o0 = ZERO16, o1 = ZERO16;
  const int NCH = F_ / 2 / 64;             // 32 chunks in this k-half

  for (int c = 0; c < NCH; ++c) {
    const int cur = (c & 1) * 4096;
    const int nxt = cur ^ 4096;
    __syncthreads();                       // buf[cur] staged; old readers done
    if (c + 1 < NCH) {
#pragma unroll
      for (int p = 0; p < 2; ++p) {
        stage16(sm + nxt, kbase + (size_t)(c + 1) * 64 * I_, p * 256 + t, 64);
        stage16(sm + 8192 + nxt, vbase + (size_t)(c + 1) * 64, p * 256 + t, F_);
      }
    }

    // S^T = K x Q(own 32q): rows=k (two 32-halves), cols=q
    const u16* Kc = sm + cur;
    f32x16 s0 = ZERO16, s1 = ZERO16;
#pragma unroll
    for (int ic = 0; ic < 4; ++ic) {
      const bf16x8 ak0 = ldfrag(Kc, l31, ic * 2 + lh);
      const bf16x8 ak1 = ldfrag(Kc + 32 * 64, l31, ic * 2 + lh);
      s0 = MFMA32(ak0, qf[ic], s0);
      s1 = MFMA32(ak1, qf[ic], s1);
    }

    // exp2 + in-register transpose into PV A-fragments (k-blocks of 16)
    bf16x8 af[4];
    build_af(s0, af[0], af[1]);
    build_af(s1, af[2], af[3]);

    // O += P(32q x 64k) * V'(64k x 64i), two i-halves
    const u16* Vc = sm + 8192 + cur;
#pragma unroll
    for (int kb4 = 0; kb4 < 4; ++kb4) {
      const bf16x8 bv0 = ldfrag(Vc, l31, kb4 * 2 + lh);
      const bf16x8 bv1 = ldfrag(Vc + 32 * 64, l31, kb4 * 2 + lh);
      o0 = MFMA32(af[kb4], bv0, o0);
      o1 = MFMA32(af[kb4], bv1, o1);
    }
  }

  float* dst = (ks == 0 ? outp : pout) + ((size_t)b * F_ + q0 + w * 32) * I_;
#pragma unroll
  for (int r = 0; r < 16; ++r) {
    const int qr = (r & 3) + 8 * (r >> 2) + 4 * lh;
    dst[(size_t)qr * I_ + l31]      = o0[r];
    dst[(size_t)qr * I_ + 32 + l31] = o1[r];
  }
}

// ---------------------------------------------------------------------------
// Kernel 5: out += partial (k-split reduction).
// ---------------------------------------------------------------------------
__global__ __launch_bounds__(256) void reduce_k(float* __restrict__ outp,
                                                const float* __restrict__ p1) {
  const size_t i = ((size_t)blockIdx.x * 256 + threadIdx.x) * 4;
  float4 a = *(const float4*)(outp + i);
  const float4 bq = *(const float4*)(p1 + i);
  a.x += bq.x; a.y += bq.y; a.z += bq.z; a.w += bq.w;
  *(float4*)(outp + i) = a;
}

// ---------------------------------------------------------------------------
extern "C" void kernel_launch(void* const* d_in, const int* in_sizes, int n_in,
                              void* d_out, int out_size, void* d_ws,
                              size_t ws_size, hipStream_t stream) {
  const float* x  = (const float*)d_in[0];
  const float* Wq = (const float*)d_in[1];
  const float* Wk = (const float*)d_in[2];
  const float* Wv = (const float*)d_in[3];
  float* out = (float*)d_out;

  // workspace: qn, kn, vt (bf16, B*F*I each); zp (f32 [NQS][B][F]);
  //            pout (f32 [B][F][I] k-split partial)
  const size_t NBF = (size_t)B_ * F_ * I_;
  u16* qn    = (u16*)d_ws;
  u16* kn    = qn + NBF;
  u16* vt    = kn + NBF;
  float* zp  = (float*)(vt + NBF);
  float* pout = zp + (size_t)NQS * B_ * F_;

  qkv_ln_k<<<dim3(F_ / 64, B_), 256, 0, stream>>>(x, Wq, Wk, Wv, qn, kn, vt);
  attn_stats_k<<<dim3(F_ / 256, B_, NQS), 512, 0, stream>>>(qn, kn, zp);
  vscale_k<<<dim3(I_ * F_ / 2048, B_), 256, 0, stream>>>(vt, zp);
  attn_out_k<<<dim3(F_ / 128, B_, 2), 256, 0, stream>>>(qn, kn, vt, out, pout);
  reduce_k<<<dim3((int)(NBF / 1024)), 256, 0, stream>>>(out, pout);
}